// Round 1
// baseline (504.728 us; speedup 1.0000x reference)
//
#include <hip/hip_runtime.h>

using u16 = unsigned short;
typedef __attribute__((ext_vector_type(8))) short short8;
typedef __attribute__((ext_vector_type(4))) float floatx4;

#define Bb 8
#define NQ 1024
#define NK 2048
#define DD 512

__device__ __forceinline__ u16 f2bf(float f) {
  union { float f; unsigned u; } x; x.f = f;
  unsigned r = (x.u + 0x7fffu + ((x.u >> 16) & 1u)) >> 16;
  return (u16)r;
}
__device__ __forceinline__ float bf2f(u16 u) {
  union { unsigned u; float f; } x; x.u = ((unsigned)u) << 16; return x.f;
}
__device__ __forceinline__ float wave_sum(float v) {
#pragma unroll
  for (int off = 32; off > 0; off >>= 1) v += __shfl_down(v, off, 64);
  return v;
}

// ---------------- LayerNorm -> bf16 ----------------
__global__ __launch_bounds__(256) void ln_bf16(const float* __restrict__ X,
    const float* __restrict__ G, const float* __restrict__ Bv,
    u16* __restrict__ Y) {
  const int row = blockIdx.x, t = threadIdx.x;
  const float2 v = ((const float2*)(X + (long)row * DD))[t];
  float s = v.x + v.y, ss = v.x * v.x + v.y * v.y;
  __shared__ float red[8];
  float a = wave_sum(s), b = wave_sum(ss);
  if ((t & 63) == 0) { red[t >> 6] = a; red[4 + (t >> 6)] = b; }
  __syncthreads();
  float tot = red[0] + red[1] + red[2] + red[3];
  float tss = red[4] + red[5] + red[6] + red[7];
  float mu = tot * (1.f / DD);
  float var = tss * (1.f / DD) - mu * mu;
  float rs = rsqrtf(var + 1e-5f);
  float2 g2 = ((const float2*)G)[t];
  float2 b2 = ((const float2*)Bv)[t];
  ushort2 o;
  o.x = f2bf((v.x - mu) * rs * g2.x + b2.x);
  o.y = f2bf((v.y - mu) * rs * g2.y + b2.y);
  ((ushort2*)(Y + (long)row * DD))[t] = o;
}

// ---------------- fp32 -> bf16 convert (weights) ----------------
__global__ __launch_bounds__(256) void cvt_bf16(const float* __restrict__ S,
                                                u16* __restrict__ Dst) {
  int i = (blockIdx.x * 256 + threadIdx.x) * 4;
  float4 v = *(const float4*)(S + i);
  ushort4 o;
  o.x = f2bf(v.x); o.y = f2bf(v.y); o.z = f2bf(v.z); o.w = f2bf(v.w);
  *(ushort4*)(Dst + i) = o;
}

// ---------------- GEMM (B^T form): C[m,n] = sum_k A[m,k]*B[n,k] ----------------
// epi 0: bf16 out, C[bz*sCb + m*ldC + n] = val*scale + bias[n]
// epi 1: bf16 out transposed-batched: C[(m>>11)*(512*2048) + n*2048 + (m&2047)]
// epi 2: fp32 out, no bias
__device__ __forceinline__ void gload16(const u16* g, const u16* l) {
  __builtin_amdgcn_global_load_lds(
      (const __attribute__((address_space(1))) void*)g,
      (__attribute__((address_space(3))) void*)l, 16, 0, 0);
}

__global__ __launch_bounds__(256) void gemm_bt(
    const u16* __restrict__ A, const u16* __restrict__ B,
    const float* __restrict__ bias, void* __restrict__ Cout,
    int K, long sAb, long sBb, long sCb, int ldC, float scale, int epi) {
  __shared__ u16 lA[128 * 32];
  __shared__ u16 lB[128 * 32];
  const int bz = blockIdx.z;
  A += (long)bz * sAb;
  B += (long)bz * sBb;
  const int m0 = blockIdx.x * 128, n0 = blockIdx.y * 128;
  const int t = threadIdx.x, wave = t >> 6, lane = t & 63;
  const int fm = lane & 15, fq = lane >> 4;
  const int wm = (wave >> 1) * 64, wn = (wave & 1) * 64;

  const u16* gA = A + (long)(m0 + wave * 16 + (lane >> 2)) * K + (lane & 3) * 8;
  const u16* gB = B + (long)(n0 + wave * 16 + (lane >> 2)) * K + (lane & 3) * 8;
  const long g64 = (long)64 * K;
  u16* lAw0 = lA + (wave * 16) * 32;
  u16* lAw1 = lA + (64 + wave * 16) * 32;
  u16* lBw0 = lB + (wave * 16) * 32;
  u16* lBw1 = lB + (64 + wave * 16) * 32;

  floatx4 acc[4][4];
#pragma unroll
  for (int x = 0; x < 4; ++x)
#pragma unroll
    for (int y = 0; y < 4; ++y) { floatx4 z = {0.f, 0.f, 0.f, 0.f}; acc[x][y] = z; }

  const int nkt = K >> 5;
  for (int kt = 0; kt < nkt; ++kt) {
    gload16(gA, lAw0);
    gload16(gA + g64, lAw1);
    gload16(gB, lBw0);
    gload16(gB + g64, lBw1);
    gA += 32; gB += 32;
    __syncthreads();
    short8 af[4], bfr[4];
#pragma unroll
    for (int x = 0; x < 4; ++x)
      af[x] = *(const short8*)&lA[(wm + x * 16 + fm) * 32 + fq * 8];
#pragma unroll
    for (int y = 0; y < 4; ++y)
      bfr[y] = *(const short8*)&lB[(wn + y * 16 + fm) * 32 + fq * 8];
#pragma unroll
    for (int x = 0; x < 4; ++x)
#pragma unroll
      for (int y = 0; y < 4; ++y)
        acc[x][y] = __builtin_amdgcn_mfma_f32_16x16x32_bf16(af[x], bfr[y], acc[x][y], 0, 0, 0);
    __syncthreads();
  }

#pragma unroll
  for (int x = 0; x < 4; ++x) {
#pragma unroll
    for (int y = 0; y < 4; ++y) {
#pragma unroll
      for (int r = 0; r < 4; ++r) {
        int row = m0 + wm + x * 16 + fq * 4 + r;
        int col = n0 + wn + y * 16 + fm;
        float val = acc[x][y][r] * scale;
        if (bias) val += bias[col];
        if (epi == 0) {
          ((u16*)Cout)[(long)bz * sCb + (long)row * ldC + col] = f2bf(val);
        } else if (epi == 1) {
          ((u16*)Cout)[(long)(row >> 11) * (512L * 2048) + (long)col * 2048 + (row & 2047)] = f2bf(val);
        } else {
          ((float*)Cout)[(long)bz * sCb + (long)row * ldC + col] = val;
        }
      }
    }
  }
}

// ---------------- column softmax stats (max, 1/sumexp over i per column j) ----------------
__global__ __launch_bounds__(256) void colstats(const u16* __restrict__ S,
                                                float2* __restrict__ MZ) {
  const int b = blockIdx.y;
  const int j = blockIdx.x * 256 + threadIdx.x;
  const u16* p = S + (long)b * (NQ * NK) + j;
  float m = -1e30f;
  for (int i = 0; i < NQ; ++i) m = fmaxf(m, bf2f(p[(long)i * NK]));
  float z = 0.f;
  for (int i = 0; i < NQ; ++i) z += __expf(bf2f(p[(long)i * NK]) - m);
  float2 o; o.x = m; o.y = 1.0f / z;
  MZ[b * NK + j] = o;
}

// ---------------- row renorm: P = (exp(S-M)/Z + EPS) / R, in place ----------------
__global__ __launch_bounds__(256) void rowsoftmax(u16* __restrict__ S,
                                                  const float2* __restrict__ MZ) {
  const int row = blockIdx.x;
  const int b = row >> 10, i = row & 1023;
  u16* p = S + (long)b * (NQ * NK) + (long)i * NK;
  const float2* mz = MZ + b * NK;
  const int t = threadIdx.x;
  float e[8];
  float sum = 0.f;
#pragma unroll
  for (int r = 0; r < 8; ++r) {
    int j = r * 256 + t;
    float2 z = mz[j];
    float s = bf2f(p[j]);
    float ee = __expf(s - z.x) * z.y;
    e[r] = ee;
    sum += ee;
  }
  __shared__ float red[4];
  float a = wave_sum(sum);
  if ((t & 63) == 0) red[t >> 6] = a;
  __syncthreads();
  float R = red[0] + red[1] + red[2] + red[3] + 2048.f * 1e-8f;
  float invR = 1.0f / R;
#pragma unroll
  for (int r = 0; r < 8; ++r) {
    int j = r * 256 + t;
    p[j] = f2bf((e[r] + 1e-8f) * invR);
  }
}

extern "C" void kernel_launch(void* const* d_in, const int* in_sizes, int n_in,
                              void* d_out, int out_size, void* d_ws, size_t ws_size,
                              hipStream_t stream) {
  const float* inputs  = (const float*)d_in[0];
  const float* context = (const float*)d_in[1];
  const float* ln_in_g = (const float*)d_in[2];
  const float* ln_in_b = (const float*)d_in[3];
  const float* ln_ctx_g = (const float*)d_in[4];
  const float* ln_ctx_b = (const float*)d_in[5];
  const float* Wq = (const float*)d_in[6];
  const float* bq = (const float*)d_in[7];
  const float* Wk = (const float*)d_in[8];
  const float* bk = (const float*)d_in[9];
  const float* Wv = (const float*)d_in[10];
  const float* bv = (const float*)d_in[11];
  float* out = (float*)d_out;

  // workspace layout (u16 elements unless noted)
  u16* ws = (u16*)d_ws;
  u16* xb  = ws;                       // [8192][512]
  u16* cb  = xb + 8192L * 512;         // [16384][512]
  u16* wqb = cb + 16384L * 512;        // [512][512]
  u16* wkb = wqb + 512L * 512;
  u16* wvb = wkb + 512L * 512;
  u16* qb  = wvb + 512L * 512;         // [8192][512]
  u16* kb  = qb + 8192L * 512;         // [16384][512]
  u16* vT  = kb + 16384L * 512;        // [8][512][2048]
  u16* S   = vT + 8L * 512 * 2048;     // [8][1024][2048]  (becomes P in place)
  float2* MZ = (float2*)(S + 8L * 1024 * 2048);  // [8][2048]

  const float scale = 0.04419417382415922f;  // 512^-0.5

  ln_bf16<<<8192, 256, 0, stream>>>(inputs, ln_in_g, ln_in_b, xb);
  ln_bf16<<<16384, 256, 0, stream>>>(context, ln_ctx_g, ln_ctx_b, cb);
  cvt_bf16<<<256, 256, 0, stream>>>(Wq, wqb);
  cvt_bf16<<<256, 256, 0, stream>>>(Wk, wkb);
  cvt_bf16<<<256, 256, 0, stream>>>(Wv, wvb);

  // q = xb @ Wq^T + bq  -> qb [8192,512]
  gemm_bt<<<dim3(64, 4, 1), 256, 0, stream>>>(xb, wqb, bq, qb,
      512, 0L, 0L, 0L, 512, 1.0f, 0);
  // k = cb @ Wk^T + bk  -> kb [16384,512]
  gemm_bt<<<dim3(128, 4, 1), 256, 0, stream>>>(cb, wkb, bk, kb,
      512, 0L, 0L, 0L, 512, 1.0f, 0);
  // v = cb @ Wv^T + bv  -> vT [8][512][2048] (transposed epilogue)
  gemm_bt<<<dim3(128, 4, 1), 256, 0, stream>>>(cb, wvb, bv, vT,
      512, 0L, 0L, 0L, 0, 1.0f, 1);
  // S[b] = qb[b] @ kb[b]^T * scale -> [8][1024][2048] bf16
  gemm_bt<<<dim3(8, 16, 8), 256, 0, stream>>>(qb, kb, nullptr, S,
      512, 1024L * 512, 2048L * 512, 1024L * 2048, 2048, scale, 0);
  // column softmax stats over i (per b, j)
  colstats<<<dim3(8, 8), 256, 0, stream>>>(S, MZ);
  // row renorm -> P (in place)
  rowsoftmax<<<8192, 256, 0, stream>>>(S, MZ);
  // updates[b] = P[b] @ vT[b]^T -> d_out fp32 [8][1024][512]
  gemm_bt<<<dim3(8, 4, 8), 256, 0, stream>>>(S, vT, nullptr, out,
      2048, 1024L * 2048, 512L * 2048, 1024L * 512, 512, 1.0f, 2);
}

// Round 2
// 349.712 us; speedup vs baseline: 1.4433x; 1.4433x over previous
//
#include <hip/hip_runtime.h>

using u16 = unsigned short;
typedef __attribute__((ext_vector_type(8))) short short8;
typedef __attribute__((ext_vector_type(4))) float floatx4;

#define Bb 8
#define NQ 1024
#define NK 2048
#define DD 512

__device__ __forceinline__ u16 f2bf(float f) {
  union { float f; unsigned u; } x; x.f = f;
  unsigned r = (x.u + 0x7fffu + ((x.u >> 16) & 1u)) >> 16;
  return (u16)r;
}
__device__ __forceinline__ float bf2f(u16 u) {
  union { unsigned u; float f; } x; x.u = ((unsigned)u) << 16; return x.f;
}
__device__ __forceinline__ float wave_sum(float v) {
#pragma unroll
  for (int off = 32; off > 0; off >>= 1) v += __shfl_down(v, off, 64);
  return v;
}

// ---------------- LayerNorm -> bf16 ----------------
__global__ __launch_bounds__(256) void ln_bf16(const float* __restrict__ X,
    const float* __restrict__ G, const float* __restrict__ Bv,
    u16* __restrict__ Y) {
  const int row = blockIdx.x, t = threadIdx.x;
  const float2 v = ((const float2*)(X + (long)row * DD))[t];
  float s = v.x + v.y, ss = v.x * v.x + v.y * v.y;
  __shared__ float red[8];
  float a = wave_sum(s), b = wave_sum(ss);
  if ((t & 63) == 0) { red[t >> 6] = a; red[4 + (t >> 6)] = b; }
  __syncthreads();
  float tot = red[0] + red[1] + red[2] + red[3];
  float tss = red[4] + red[5] + red[6] + red[7];
  float mu = tot * (1.f / DD);
  float var = tss * (1.f / DD) - mu * mu;
  float rs = rsqrtf(var + 1e-5f);
  float2 g2 = ((const float2*)G)[t];
  float2 b2 = ((const float2*)Bv)[t];
  ushort2 o;
  o.x = f2bf((v.x - mu) * rs * g2.x + b2.x);
  o.y = f2bf((v.y - mu) * rs * g2.y + b2.y);
  ((ushort2*)(Y + (long)row * DD))[t] = o;
}

// ---------------- fp32 -> bf16 convert (weights) ----------------
__global__ __launch_bounds__(256) void cvt_bf16(const float* __restrict__ S,
                                                u16* __restrict__ Dst) {
  int i = (blockIdx.x * 256 + threadIdx.x) * 4;
  float4 v = *(const float4*)(S + i);
  ushort4 o;
  o.x = f2bf(v.x); o.y = f2bf(v.y); o.z = f2bf(v.z); o.w = f2bf(v.w);
  *(ushort4*)(Dst + i) = o;
}

// ---------------- GEMM (B^T form): C[m,n] = sum_k A[m,k]*B[n,k] ----------------
// epi 0: bf16 out, C[bz*sCb + m*ldC + n] = val*scale + bias[n]
// epi 1: bf16 out transposed-batched: C[(m>>11)*(512*2048) + n*2048 + (m&2047)]
// epi 2: fp32 out, no bias
// epi 3: bf16 out, E = exp(val*scale)
__device__ __forceinline__ void gload16(const u16* g, const u16* l) {
  __builtin_amdgcn_global_load_lds(
      (const __attribute__((address_space(1))) void*)g,
      (__attribute__((address_space(3))) void*)l, 16, 0, 0);
}

__global__ __launch_bounds__(256) void gemm_bt(
    const u16* __restrict__ A, const u16* __restrict__ B,
    const float* __restrict__ bias, void* __restrict__ Cout,
    int K, long sAb, long sBb, long sCb, int ldC, float scale, int epi) {
  __shared__ u16 lA[128 * 32];
  __shared__ u16 lB[128 * 32];
  const int bz = blockIdx.z;
  A += (long)bz * sAb;
  B += (long)bz * sBb;
  const int m0 = blockIdx.x * 128, n0 = blockIdx.y * 128;
  const int t = threadIdx.x, wave = t >> 6, lane = t & 63;
  const int fm = lane & 15, fq = lane >> 4;
  const int wm = (wave >> 1) * 64, wn = (wave & 1) * 64;

  const u16* gA = A + (long)(m0 + wave * 16 + (lane >> 2)) * K + (lane & 3) * 8;
  const u16* gB = B + (long)(n0 + wave * 16 + (lane >> 2)) * K + (lane & 3) * 8;
  const long g64 = (long)64 * K;
  u16* lAw0 = lA + (wave * 16) * 32;
  u16* lAw1 = lA + (64 + wave * 16) * 32;
  u16* lBw0 = lB + (wave * 16) * 32;
  u16* lBw1 = lB + (64 + wave * 16) * 32;

  floatx4 acc[4][4];
#pragma unroll
  for (int x = 0; x < 4; ++x)
#pragma unroll
    for (int y = 0; y < 4; ++y) { floatx4 z = {0.f, 0.f, 0.f, 0.f}; acc[x][y] = z; }

  const int nkt = K >> 5;
  for (int kt = 0; kt < nkt; ++kt) {
    gload16(gA, lAw0);
    gload16(gA + g64, lAw1);
    gload16(gB, lBw0);
    gload16(gB + g64, lBw1);
    gA += 32; gB += 32;
    __syncthreads();
    short8 af[4], bfr[4];
#pragma unroll
    for (int x = 0; x < 4; ++x)
      af[x] = *(const short8*)&lA[(wm + x * 16 + fm) * 32 + fq * 8];
#pragma unroll
    for (int y = 0; y < 4; ++y)
      bfr[y] = *(const short8*)&lB[(wn + y * 16 + fm) * 32 + fq * 8];
#pragma unroll
    for (int x = 0; x < 4; ++x)
#pragma unroll
      for (int y = 0; y < 4; ++y)
        acc[x][y] = __builtin_amdgcn_mfma_f32_16x16x32_bf16(af[x], bfr[y], acc[x][y], 0, 0, 0);
    __syncthreads();
  }

#pragma unroll
  for (int x = 0; x < 4; ++x) {
#pragma unroll
    for (int y = 0; y < 4; ++y) {
#pragma unroll
      for (int r = 0; r < 4; ++r) {
        int row = m0 + wm + x * 16 + fq * 4 + r;
        int col = n0 + wn + y * 16 + fm;
        float val = acc[x][y][r] * scale;
        if (bias) val += bias[col];
        if (epi == 0) {
          ((u16*)Cout)[(long)bz * sCb + (long)row * ldC + col] = f2bf(val);
        } else if (epi == 1) {
          ((u16*)Cout)[(long)(row >> 11) * (512L * 2048) + (long)col * 2048 + (row & 2047)] = f2bf(val);
        } else if (epi == 3) {
          ((u16*)Cout)[(long)bz * sCb + (long)row * ldC + col] = f2bf(__expf(val));
        } else {
          ((float*)Cout)[(long)bz * sCb + (long)row * ldC + col] = val;
        }
      }
    }
  }
}

// ---------------- zero init ----------------
__global__ __launch_bounds__(256) void zerof(float* __restrict__ p) {
  p[blockIdx.x * 256 + threadIdx.x] = 0.f;
}

// ---------------- parallel column sum of E (bf16) into Z (fp32, atomics) -------
__global__ __launch_bounds__(256) void colsum(const u16* __restrict__ E,
                                              float* __restrict__ Z) {
  const int b = blockIdx.y;
  const int i0 = blockIdx.x * 32;
  const int t = threadIdx.x;
  const u16* p = E + (long)b * (NQ * NK) + (long)i0 * NK + t * 8;
  float s[8];
#pragma unroll
  for (int k = 0; k < 8; ++k) s[k] = 0.f;
  for (int r = 0; r < 32; ++r) {
    short8 v = *(const short8*)(p + (long)r * NK);
#pragma unroll
    for (int k = 0; k < 8; ++k) s[k] += bf2f((u16)v[k]);
  }
  float* zp = Z + b * NK + t * 8;
#pragma unroll
  for (int k = 0; k < 8; ++k) atomicAdd(zp + k, s[k]);
}

// ---------------- reciprocal in place ----------------
__global__ __launch_bounds__(256) void recipf(float* __restrict__ p) {
  int i = blockIdx.x * 256 + threadIdx.x;
  p[i] = 1.0f / p[i];
}

// ---------------- row renorm: P = (E*invZ + EPS) / R, in place ----------------
__global__ __launch_bounds__(256) void rowsoftmax(u16* __restrict__ S,
                                                  const float* __restrict__ invZ) {
  const int row = blockIdx.x;
  const int b = row >> 10, i = row & 1023;
  u16* p = S + (long)b * (NQ * NK) + (long)i * NK;
  const float* zp = invZ + b * NK;
  const int t = threadIdx.x;
  const int j0 = t * 8;
  short8 v = *(const short8*)(p + j0);
  float4 z0 = *(const float4*)(zp + j0);
  float4 z1 = *(const float4*)(zp + j0 + 4);
  float e[8];
  e[0] = bf2f((u16)v[0]) * z0.x; e[1] = bf2f((u16)v[1]) * z0.y;
  e[2] = bf2f((u16)v[2]) * z0.z; e[3] = bf2f((u16)v[3]) * z0.w;
  e[4] = bf2f((u16)v[4]) * z1.x; e[5] = bf2f((u16)v[5]) * z1.y;
  e[6] = bf2f((u16)v[6]) * z1.z; e[7] = bf2f((u16)v[7]) * z1.w;
  float sum = 0.f;
#pragma unroll
  for (int k = 0; k < 8; ++k) sum += e[k];
  __shared__ float red[4];
  float a = wave_sum(sum);
  if ((t & 63) == 0) red[t >> 6] = a;
  __syncthreads();
  float R = red[0] + red[1] + red[2] + red[3] + 2048.f * 1e-8f;
  float invR = 1.0f / R;
  short8 o;
#pragma unroll
  for (int k = 0; k < 8; ++k) o[k] = (short)f2bf((e[k] + 1e-8f) * invR);
  *(short8*)(p + j0) = o;
}

extern "C" void kernel_launch(void* const* d_in, const int* in_sizes, int n_in,
                              void* d_out, int out_size, void* d_ws, size_t ws_size,
                              hipStream_t stream) {
  const float* inputs  = (const float*)d_in[0];
  const float* context = (const float*)d_in[1];
  const float* ln_in_g = (const float*)d_in[2];
  const float* ln_in_b = (const float*)d_in[3];
  const float* ln_ctx_g = (const float*)d_in[4];
  const float* ln_ctx_b = (const float*)d_in[5];
  const float* Wq = (const float*)d_in[6];
  const float* bq = (const float*)d_in[7];
  const float* Wk = (const float*)d_in[8];
  const float* bk = (const float*)d_in[9];
  const float* Wv = (const float*)d_in[10];
  const float* bv = (const float*)d_in[11];
  float* out = (float*)d_out;

  // workspace layout (u16 elements unless noted)
  u16* ws = (u16*)d_ws;
  u16* xb  = ws;                       // [8192][512]
  u16* cb  = xb + 8192L * 512;         // [16384][512]
  u16* wqb = cb + 16384L * 512;        // [512][512]
  u16* wkb = wqb + 512L * 512;
  u16* wvb = wkb + 512L * 512;
  u16* qb  = wvb + 512L * 512;         // [8192][512]
  u16* kb  = qb + 8192L * 512;         // [16384][512]
  u16* vT  = kb + 16384L * 512;        // [8][512][2048]
  u16* S   = vT + 8L * 512 * 2048;     // [8][1024][2048]  E then P in place
  float* Z = (float*)(S + 8L * 1024 * 2048);  // [8][2048]

  const float scale = 0.04419417382415922f;  // 512^-0.5

  ln_bf16<<<8192, 256, 0, stream>>>(inputs, ln_in_g, ln_in_b, xb);
  ln_bf16<<<16384, 256, 0, stream>>>(context, ln_ctx_g, ln_ctx_b, cb);
  cvt_bf16<<<256, 256, 0, stream>>>(Wq, wqb);
  cvt_bf16<<<256, 256, 0, stream>>>(Wk, wkb);
  cvt_bf16<<<256, 256, 0, stream>>>(Wv, wvb);
  zerof<<<64, 256, 0, stream>>>(Z);

  // q = xb @ Wq^T + bq  -> qb [8192,512]
  gemm_bt<<<dim3(64, 4, 1), 256, 0, stream>>>(xb, wqb, bq, qb,
      512, 0L, 0L, 0L, 512, 1.0f, 0);
  // k = cb @ Wk^T + bk  -> kb [16384,512]
  gemm_bt<<<dim3(128, 4, 1), 256, 0, stream>>>(cb, wkb, bk, kb,
      512, 0L, 0L, 0L, 512, 1.0f, 0);
  // v = cb @ Wv^T + bv  -> vT [8][512][2048] (transposed epilogue)
  gemm_bt<<<dim3(128, 4, 1), 256, 0, stream>>>(cb, wvb, bv, vT,
      512, 0L, 0L, 0L, 0, 1.0f, 1);
  // E[b] = exp(qb[b] @ kb[b]^T * scale) -> [8][1024][2048] bf16
  gemm_bt<<<dim3(8, 16, 8), 256, 0, stream>>>(qb, kb, nullptr, S,
      512, 1024L * 512, 2048L * 512, 1024L * 2048, 2048, scale, 3);
  // Z[b][j] = sum_i E[b][i][j]
  colsum<<<dim3(32, 8), 256, 0, stream>>>(S, Z);
  recipf<<<64, 256, 0, stream>>>(Z);
  // row renorm -> P (in place)
  rowsoftmax<<<8192, 256, 0, stream>>>(S, Z);
  // updates[b] = P[b] @ vT[b]^T -> d_out fp32 [8][1024][512]
  gemm_bt<<<dim3(8, 4, 8), 256, 0, stream>>>(S, vT, nullptr, out,
      2048, 1024L * 2048, 512L * 2048, 1024L * 512, 512, 1.0f, 2);
}

// Round 3
// 274.104 us; speedup vs baseline: 1.8414x; 1.2758x over previous
//
#include <hip/hip_runtime.h>

using u16 = unsigned short;
typedef __attribute__((ext_vector_type(8))) short short8;
typedef __attribute__((ext_vector_type(4))) float floatx4;

#define NQ 1024
#define NK 2048
#define DD 512

__device__ __forceinline__ u16 f2bf(float f) {
  union { float f; unsigned u; } x; x.f = f;
  unsigned r = (x.u + 0x7fffu + ((x.u >> 16) & 1u)) >> 16;
  return (u16)r;
}
__device__ __forceinline__ float bf2f(u16 u) {
  union { unsigned u; float f; } x; x.u = ((unsigned)u) << 16; return x.f;
}
__device__ __forceinline__ float wave_sum(float v) {
#pragma unroll
  for (int off = 32; off > 0; off >>= 1) v += __shfl_down(v, off, 64);
  return v;
}

// ---------------- LayerNorm -> bf16 ----------------
__global__ __launch_bounds__(256) void ln_bf16(const float* __restrict__ X,
    const float* __restrict__ G, const float* __restrict__ Bv,
    u16* __restrict__ Y) {
  const int row = blockIdx.x, t = threadIdx.x;
  const float2 v = ((const float2*)(X + (long)row * DD))[t];
  float s = v.x + v.y, ss = v.x * v.x + v.y * v.y;
  __shared__ float red[8];
  float a = wave_sum(s), b = wave_sum(ss);
  if ((t & 63) == 0) { red[t >> 6] = a; red[4 + (t >> 6)] = b; }
  __syncthreads();
  float tot = red[0] + red[1] + red[2] + red[3];
  float tss = red[4] + red[5] + red[6] + red[7];
  float mu = tot * (1.f / DD);
  float var = tss * (1.f / DD) - mu * mu;
  float rs = rsqrtf(var + 1e-5f);
  float2 g2 = ((const float2*)G)[t];
  float2 b2 = ((const float2*)Bv)[t];
  ushort2 o;
  o.x = f2bf((v.x - mu) * rs * g2.x + b2.x);
  o.y = f2bf((v.y - mu) * rs * g2.y + b2.y);
  ((ushort2*)(Y + (long)row * DD))[t] = o;
}

// ---------------- fp32 -> bf16 convert (weights) ----------------
__global__ __launch_bounds__(256) void cvt_bf16(const float* __restrict__ S,
                                                u16* __restrict__ Dst) {
  int i = (blockIdx.x * 256 + threadIdx.x) * 4;
  float4 v = *(const float4*)(S + i);
  ushort4 o;
  o.x = f2bf(v.x); o.y = f2bf(v.y); o.z = f2bf(v.z); o.w = f2bf(v.w);
  *(ushort4*)(Dst + i) = o;
}

__global__ __launch_bounds__(256) void zerof(float* __restrict__ p) {
  p[blockIdx.x * 256 + threadIdx.x] = 0.f;
}
__global__ __launch_bounds__(256) void recipf(float* __restrict__ p) {
  int i = blockIdx.x * 256 + threadIdx.x;
  p[i] = 1.0f / p[i];
}

// ---------------- GEMM (B^T form): C[m,n] = sum_k A[m,k]*B[n,k] ----------------
// epi 0: bf16 out, C = val*scale + bias[n]
// epi 3: QK: bf16 E = exp(val*scale); column sums atomicAdd into aux0 (Z)
// epi 4: v-proj: val=acc+bias; store bf16 val*invZ[b][j] transposed
//        [b][col][j]; unscaled column sums atomicAdd into aux0 (colV)
// epi 5: PV split-K: fp32 partial into Cout[kh][b][row][col]
__device__ __forceinline__ void gload16(const u16* g, const u16* l) {
  __builtin_amdgcn_global_load_lds(
      (const __attribute__((address_space(1))) void*)g,
      (__attribute__((address_space(3))) void*)l, 16, 0, 0);
}

__global__ __launch_bounds__(256) void gemm_bt(
    const u16* __restrict__ A, const u16* __restrict__ B,
    const float* __restrict__ bias, void* __restrict__ Cout,
    int K, int lda, int ldb, long sAb, long sBb, long sCb, int ldC,
    float scale, int epi, float* __restrict__ aux0,
    const float* __restrict__ aux1) {
  __shared__ u16 lA[128 * 32];
  __shared__ u16 lB[128 * 32];
  int bz = blockIdx.z, b = bz, kh = 0;
  if (epi == 5) { b = bz >> 1; kh = bz & 1; }
  A += (long)b * sAb + (long)kh * 1024;
  B += (long)b * sBb + (long)kh * 1024;
  const int m0 = blockIdx.x * 128, n0 = blockIdx.y * 128;
  const int t = threadIdx.x, wave = t >> 6, lane = t & 63;
  const int fm = lane & 15, fq = lane >> 4;
  const int wm = (wave >> 1) * 64, wn = (wave & 1) * 64;

  const u16* gA = A + (long)(m0 + wave * 16 + (lane >> 2)) * lda + (lane & 3) * 8;
  const u16* gB = B + (long)(n0 + wave * 16 + (lane >> 2)) * ldb + (lane & 3) * 8;
  const long gA64 = (long)64 * lda, gB64 = (long)64 * ldb;
  u16* lAw0 = lA + (wave * 16) * 32;
  u16* lAw1 = lA + (64 + wave * 16) * 32;
  u16* lBw0 = lB + (wave * 16) * 32;
  u16* lBw1 = lB + (64 + wave * 16) * 32;

  floatx4 acc[4][4];
#pragma unroll
  for (int x = 0; x < 4; ++x)
#pragma unroll
    for (int y = 0; y < 4; ++y) { floatx4 z = {0.f, 0.f, 0.f, 0.f}; acc[x][y] = z; }

  const int nkt = K >> 5;
  for (int kt = 0; kt < nkt; ++kt) {
    gload16(gA, lAw0);
    gload16(gA + gA64, lAw1);
    gload16(gB, lBw0);
    gload16(gB + gB64, lBw1);
    gA += 32; gB += 32;
    __syncthreads();
    short8 af[4], bfr[4];
#pragma unroll
    for (int x = 0; x < 4; ++x)
      af[x] = *(const short8*)&lA[(wm + x * 16 + fm) * 32 + fq * 8];
#pragma unroll
    for (int y = 0; y < 4; ++y)
      bfr[y] = *(const short8*)&lB[(wn + y * 16 + fm) * 32 + fq * 8];
#pragma unroll
    for (int x = 0; x < 4; ++x)
#pragma unroll
      for (int y = 0; y < 4; ++y)
        acc[x][y] = __builtin_amdgcn_mfma_f32_16x16x32_bf16(af[x], bfr[y], acc[x][y], 0, 0, 0);
    __syncthreads();
  }

  if (epi == 0) {
#pragma unroll
    for (int x = 0; x < 4; ++x)
#pragma unroll
      for (int y = 0; y < 4; ++y)
#pragma unroll
        for (int r = 0; r < 4; ++r) {
          int row = m0 + wm + x * 16 + fq * 4 + r;
          int col = n0 + wn + y * 16 + fm;
          float val = acc[x][y][r] * scale + bias[col];
          ((u16*)Cout)[(long)b * sCb + (long)row * ldC + col] = f2bf(val);
        }
  } else if (epi == 3) {
    float s[4] = {0.f, 0.f, 0.f, 0.f};
#pragma unroll
    for (int x = 0; x < 4; ++x)
#pragma unroll
      for (int y = 0; y < 4; ++y)
#pragma unroll
        for (int r = 0; r < 4; ++r) {
          int row = m0 + wm + x * 16 + fq * 4 + r;
          int col = n0 + wn + y * 16 + fm;
          float e = __expf(acc[x][y][r] * scale);
          s[y] += e;
          ((u16*)Cout)[(long)b * sCb + (long)row * ldC + col] = f2bf(e);
        }
    // column reduce: sum over fq within wave
#pragma unroll
    for (int y = 0; y < 4; ++y) {
      s[y] += __shfl_xor(s[y], 16, 64);
      s[y] += __shfl_xor(s[y], 32, 64);
    }
    float* colred = (float*)lA;
    if (t < 128) colred[t] = 0.f;
    __syncthreads();
    if (fq == 0) {
#pragma unroll
      for (int y = 0; y < 4; ++y) atomicAdd(&colred[wn + y * 16 + fm], s[y]);
    }
    __syncthreads();
    if (t < 128) atomicAdd(&aux0[b * NK + n0 + t], colred[t]);
  } else if (epi == 4) {
    const int bb = m0 >> 11;
    float s[4] = {0.f, 0.f, 0.f, 0.f};
#pragma unroll
    for (int x = 0; x < 4; ++x)
#pragma unroll
      for (int y = 0; y < 4; ++y)
#pragma unroll
        for (int r = 0; r < 4; ++r) {
          int row = m0 + wm + x * 16 + fq * 4 + r;
          int col = n0 + wn + y * 16 + fm;
          int j = row & 2047;
          float val = acc[x][y][r] + bias[col];
          s[y] += val;
          float iz = aux1[bb * NK + j];
          ((u16*)Cout)[(long)bb * (512L * 2048) + (long)col * 2048 + j] = f2bf(val * iz);
        }
#pragma unroll
    for (int y = 0; y < 4; ++y) {
      s[y] += __shfl_xor(s[y], 16, 64);
      s[y] += __shfl_xor(s[y], 32, 64);
    }
    float* colred = (float*)lA;
    if (t < 128) colred[t] = 0.f;
    __syncthreads();
    if (fq == 0) {
#pragma unroll
      for (int y = 0; y < 4; ++y) atomicAdd(&colred[wn + y * 16 + fm], s[y]);
    }
    __syncthreads();
    if (t < 128) atomicAdd(&aux0[bb * 512 + n0 + t], colred[t]);
  } else {  // epi 5
    float* Cp = (float*)Cout + (long)kh * (8L * 1024 * 512) + (long)b * sCb;
#pragma unroll
    for (int x = 0; x < 4; ++x)
#pragma unroll
      for (int y = 0; y < 4; ++y)
#pragma unroll
        for (int r = 0; r < 4; ++r) {
          int row = m0 + wm + x * 16 + fq * 4 + r;
          int col = n0 + wn + y * 16 + fm;
          Cp[(long)row * ldC + col] = acc[x][y][r];
        }
  }
}

// ---------------- R row-sums: invR[b][i] = 1/(sum_j E*invZ + NK*eps) --------
__global__ __launch_bounds__(256) void rowsumR(const u16* __restrict__ E,
    const float* __restrict__ invZ, float* __restrict__ invR) {
  const int row = blockIdx.x;
  const int b = row >> 10;
  const u16* p = E + (long)row * NK;
  const float* zp = invZ + b * NK;
  const int t = threadIdx.x, j0 = t * 8;
  short8 v = *(const short8*)(p + j0);
  float4 z0 = *(const float4*)(zp + j0);
  float4 z1 = *(const float4*)(zp + j0 + 4);
  float sum = bf2f((u16)v[0]) * z0.x + bf2f((u16)v[1]) * z0.y +
              bf2f((u16)v[2]) * z0.z + bf2f((u16)v[3]) * z0.w +
              bf2f((u16)v[4]) * z1.x + bf2f((u16)v[5]) * z1.y +
              bf2f((u16)v[6]) * z1.z + bf2f((u16)v[7]) * z1.w;
  __shared__ float red[4];
  float a = wave_sum(sum);
  if ((t & 63) == 0) red[t >> 6] = a;
  __syncthreads();
  if (t == 0) {
    float R = red[0] + red[1] + red[2] + red[3] + 2048.f * 1e-8f;
    invR[row] = 1.0f / R;
  }
}

// ---------------- PV reduce: out = (Cp0+Cp1 + eps*colV[d]) * invR[i] --------
__global__ __launch_bounds__(256) void pv_reduce(const float* __restrict__ Cp,
    const float* __restrict__ colV, const float* __restrict__ invR,
    float* __restrict__ out) {
  const long e = ((long)blockIdx.x * 256 + threadIdx.x) * 4;
  const int b = (int)(e >> 19);
  const int i = (int)((e >> 9) & 1023);
  const int d = (int)(e & 511);
  float4 a0 = *(const float4*)(Cp + e);
  float4 a1 = *(const float4*)(Cp + e + 8L * 1024 * 512);
  float4 cv = *(const float4*)(colV + b * 512 + d);
  float ir = invR[b * 1024 + i];
  float4 o;
  o.x = (a0.x + a1.x + 1e-8f * cv.x) * ir;
  o.y = (a0.y + a1.y + 1e-8f * cv.y) * ir;
  o.z = (a0.z + a1.z + 1e-8f * cv.z) * ir;
  o.w = (a0.w + a1.w + 1e-8f * cv.w) * ir;
  *(float4*)(out + e) = o;
}

extern "C" void kernel_launch(void* const* d_in, const int* in_sizes, int n_in,
                              void* d_out, int out_size, void* d_ws, size_t ws_size,
                              hipStream_t stream) {
  const float* inputs  = (const float*)d_in[0];
  const float* context = (const float*)d_in[1];
  const float* ln_in_g = (const float*)d_in[2];
  const float* ln_in_b = (const float*)d_in[3];
  const float* ln_ctx_g = (const float*)d_in[4];
  const float* ln_ctx_b = (const float*)d_in[5];
  const float* Wq = (const float*)d_in[6];
  const float* bq = (const float*)d_in[7];
  const float* Wk = (const float*)d_in[8];
  const float* bk = (const float*)d_in[9];
  const float* Wv = (const float*)d_in[10];
  const float* bv = (const float*)d_in[11];
  float* out = (float*)d_out;

  // ws layout (u16 elems). [xb qb cb] (32 MB) is reused as Cp for PV partials.
  u16* ws = (u16*)d_ws;
  u16* xb  = ws;                        // [8192][512]   dead after q-proj
  u16* qb  = xb + 8192L * 512;          // [8192][512]   dead after QK
  u16* cb  = qb + 8192L * 512;          // [16384][512]  dead after v-proj
  u16* wqb = cb + 16384L * 512;         // [512][512]
  u16* wkb = wqb + 512L * 512;
  u16* wvb = wkb + 512L * 512;
  u16* kb  = wvb + 512L * 512;          // [16384][512]
  u16* vTs = kb + 16384L * 512;         // [8][512][2048] (v*invZ, transposed)
  u16* E   = vTs + 8L * 512 * 2048;     // [8][1024][2048]
  float* Z    = (float*)(E + 8L * 1024 * 2048);  // [8][2048] -> invZ in place
  float* colV = Z + 8L * 2048;                    // [8][512]
  float* invR = colV + 8L * 512;                  // [8][1024]
  float* Cp   = (float*)ws;             // [2][8][1024][512] fp32 over xb/qb/cb

  const float scale = 0.04419417382415922f;  // 512^-0.5

  ln_bf16<<<8192, 256, 0, stream>>>(inputs, ln_in_g, ln_in_b, xb);
  ln_bf16<<<16384, 256, 0, stream>>>(context, ln_ctx_g, ln_ctx_b, cb);
  cvt_bf16<<<256, 256, 0, stream>>>(Wq, wqb);
  cvt_bf16<<<256, 256, 0, stream>>>(Wk, wkb);
  cvt_bf16<<<256, 256, 0, stream>>>(Wv, wvb);
  zerof<<<80, 256, 0, stream>>>(Z);  // Z + colV

  // q = xb @ Wq^T + bq  -> qb [8192,512]
  gemm_bt<<<dim3(64, 4, 1), 256, 0, stream>>>(xb, wqb, bq, qb,
      512, 512, 512, 0L, 0L, 0L, 512, 1.0f, 0, nullptr, nullptr);
  // k = cb @ Wk^T + bk  -> kb [16384,512]
  gemm_bt<<<dim3(128, 4, 1), 256, 0, stream>>>(cb, wkb, bk, kb,
      512, 512, 512, 0L, 0L, 0L, 512, 1.0f, 0, nullptr, nullptr);
  // E[b] = exp(qb[b] @ kb[b]^T * scale), Z[b][j] += colsums
  gemm_bt<<<dim3(8, 16, 8), 256, 0, stream>>>(qb, kb, nullptr, E,
      512, 512, 512, 1024L * 512, 2048L * 512, 1024L * 2048, 2048, scale, 3, Z, nullptr);
  recipf<<<64, 256, 0, stream>>>(Z);  // Z -> invZ
  // v-proj: vTs[b][d][j] = (cb@Wv^T+bv)*invZ, colV[b][d] += colsums
  gemm_bt<<<dim3(128, 4, 1), 256, 0, stream>>>(cb, wvb, bv, vTs,
      512, 512, 512, 0L, 0L, 0L, 0, 1.0f, 4, colV, Z);
  // invR[b][i]
  rowsumR<<<8192, 256, 0, stream>>>(E, Z, invR);
  // PV split-K=2: Cp[kh][b] = E[b][:,kh*1024:+1024] @ vTs[b][:,kh*1024:+1024]^T
  gemm_bt<<<dim3(8, 4, 16), 256, 0, stream>>>(E, vTs, nullptr, Cp,
      1024, 2048, 2048, 1024L * 2048, 512L * 2048, 1024L * 512, 512, 1.0f, 5, nullptr, nullptr);
  // out = (Cp0 + Cp1 + eps*colV) * invR
  pv_reduce<<<4096, 256, 0, stream>>>(Cp, colV, invR, out);
}

// Round 4
// 262.715 us; speedup vs baseline: 1.9212x; 1.0434x over previous
//
#include <hip/hip_runtime.h>

using u16 = unsigned short;
typedef __attribute__((ext_vector_type(8))) short short8;
typedef __attribute__((ext_vector_type(4))) float floatx4;

#define NQ 1024
#define NK 2048
#define DD 512

__device__ __forceinline__ u16 f2bf(float f) {
  union { float f; unsigned u; } x; x.f = f;
  unsigned r = (x.u + 0x7fffu + ((x.u >> 16) & 1u)) >> 16;
  return (u16)r;
}
__device__ __forceinline__ float bf2f(u16 u) {
  union { unsigned u; float f; } x; x.u = ((unsigned)u) << 16; return x.f;
}
__device__ __forceinline__ float wave_sum(float v) {
#pragma unroll
  for (int off = 32; off > 0; off >>= 1) v += __shfl_down(v, off, 64);
  return v;
}
__device__ __forceinline__ void gload16(const u16* g, const u16* l) {
  __builtin_amdgcn_global_load_lds(
      (const __attribute__((address_space(1))) void*)g,
      (__attribute__((address_space(3))) void*)l, 16, 0, 0);
}

// ---------------- fused LayerNorm (inputs + context) -> bf16 ----------------
__global__ __launch_bounds__(256) void ln_fused(
    const float* __restrict__ X1, const float* __restrict__ G1,
    const float* __restrict__ B1, u16* __restrict__ Y1,
    const float* __restrict__ X2, const float* __restrict__ G2,
    const float* __restrict__ B2, u16* __restrict__ Y2) {
  int row = blockIdx.x;
  const float *X, *G, *Bv; u16* Y;
  if (row < 8192) { X = X1; G = G1; Bv = B1; Y = Y1; }
  else { row -= 8192; X = X2; G = G2; Bv = B2; Y = Y2; }
  const int t = threadIdx.x;
  const float2 v = ((const float2*)(X + (long)row * DD))[t];
  float s = v.x + v.y, ss = v.x * v.x + v.y * v.y;
  __shared__ float red[8];
  float a = wave_sum(s), b = wave_sum(ss);
  if ((t & 63) == 0) { red[t >> 6] = a; red[4 + (t >> 6)] = b; }
  __syncthreads();
  float tot = red[0] + red[1] + red[2] + red[3];
  float tss = red[4] + red[5] + red[6] + red[7];
  float mu = tot * (1.f / DD);
  float var = tss * (1.f / DD) - mu * mu;
  float rs = rsqrtf(var + 1e-5f);
  float2 g2 = ((const float2*)G)[t];
  float2 b2 = ((const float2*)Bv)[t];
  ushort2 o;
  o.x = f2bf((v.x - mu) * rs * g2.x + b2.x);
  o.y = f2bf((v.y - mu) * rs * g2.y + b2.y);
  ((ushort2*)(Y + (long)row * DD))[t] = o;
}

// ------------- prep: 3x weight cvt to bf16 + zero Z/colV (20480 floats) -----
__global__ __launch_bounds__(256) void prep(const float* __restrict__ Wq,
    const float* __restrict__ Wk, const float* __restrict__ Wv,
    u16* __restrict__ wqb, u16* __restrict__ wkb, u16* __restrict__ wvb,
    float* __restrict__ Zero) {
  int bx = blockIdx.x;
  if (bx < 768) {
    const float* src = bx < 256 ? Wq : (bx < 512 ? Wk : Wv);
    u16* dst = bx < 256 ? wqb : (bx < 512 ? wkb : wvb);
    int i = ((bx & 255) * 256 + threadIdx.x) * 4;
    float4 v = *(const float4*)(src + i);
    ushort4 o;
    o.x = f2bf(v.x); o.y = f2bf(v.y); o.z = f2bf(v.z); o.w = f2bf(v.w);
    *(ushort4*)(dst + i) = o;
  } else {
    int i = ((bx - 768) * 256 + threadIdx.x) * 4;
    float4 z = {0.f, 0.f, 0.f, 0.f};
    *(float4*)(Zero + i) = z;
  }
}

__global__ __launch_bounds__(256) void recipf(float* __restrict__ p) {
  int i = blockIdx.x * 256 + threadIdx.x;
  p[i] = 1.0f / p[i];
}

// ---------------- GEMM (B^T form): C[m,n] = sum_k A[m,k]*B[n,k] -------------
// epi 0: bf16 out, C = val + bias[n]   (optional 2nd problem at bx>=64)
// epi 3: QK: bf16 E = exp(val*scale); col sums atomicAdd into aux0 (Z)
// epi 4: v-proj: val=acc+bias; bf16 val*invZ stored transposed [b][d][j];
//        unscaled col sums atomicAdd into aux0 (colV); aux1 = invZ
__global__ __launch_bounds__(256) void gemm_bt(
    const u16* A, const u16* B, const float* bias, void* Cout,
    const u16* A2, const u16* B2, const float* bias2, void* Cout2,
    int K, long sAb, long sBb, long sCb, int ldC,
    float scale, int epi, float* aux0, const float* aux1) {
  __shared__ u16 smem[128 * 136];   // K-loop: lA=smem[0:4096], lB=smem[4096:8192]
  __shared__ float colred[128];
  u16* lA = smem;
  u16* lB = smem + 128 * 32;

  int m0 = blockIdx.x * 128;
  if (A2 != nullptr && blockIdx.x >= 64) {
    A = A2; B = B2; bias = bias2; Cout = Cout2;
    m0 = (blockIdx.x - 64) * 128;
  }
  const int bz = blockIdx.z;
  A += (long)bz * sAb;
  B += (long)bz * sBb;
  const int n0 = blockIdx.y * 128;
  const int t = threadIdx.x, wave = t >> 6, lane = t & 63;
  const int fm = lane & 15, fq = lane >> 4;
  const int wm = (wave >> 1) * 64, wn = (wave & 1) * 64;

  const u16* gA = A + (long)(m0 + wave * 16 + (lane >> 2)) * K + (lane & 3) * 8;
  const u16* gB = B + (long)(n0 + wave * 16 + (lane >> 2)) * K + (lane & 3) * 8;
  const long g64 = (long)64 * K;
  u16* lAw0 = lA + (wave * 16) * 32;
  u16* lAw1 = lA + (64 + wave * 16) * 32;
  u16* lBw0 = lB + (wave * 16) * 32;
  u16* lBw1 = lB + (64 + wave * 16) * 32;

  floatx4 acc[4][4];
#pragma unroll
  for (int x = 0; x < 4; ++x)
#pragma unroll
    for (int y = 0; y < 4; ++y) { floatx4 z = {0.f, 0.f, 0.f, 0.f}; acc[x][y] = z; }

  const int nkt = K >> 5;
  for (int kt = 0; kt < nkt; ++kt) {
    gload16(gA, lAw0);
    gload16(gA + g64, lAw1);
    gload16(gB, lBw0);
    gload16(gB + g64, lBw1);
    gA += 32; gB += 32;
    __syncthreads();
    short8 af[4], bfr[4];
#pragma unroll
    for (int x = 0; x < 4; ++x)
      af[x] = *(const short8*)&lA[(wm + x * 16 + fm) * 32 + fq * 8];
#pragma unroll
    for (int y = 0; y < 4; ++y)
      bfr[y] = *(const short8*)&lB[(wn + y * 16 + fm) * 32 + fq * 8];
#pragma unroll
    for (int x = 0; x < 4; ++x)
#pragma unroll
      for (int y = 0; y < 4; ++y)
        acc[x][y] = __builtin_amdgcn_mfma_f32_16x16x32_bf16(af[x], bfr[y], acc[x][y], 0, 0, 0);
    __syncthreads();
  }

  // ---------------- epilogue: stage C tile in LDS, wide coalesced stores -----
  u16* sC = smem;
  float s4[4] = {0.f, 0.f, 0.f, 0.f};
  float bs[4];
  if (epi != 3) {
#pragma unroll
    for (int y = 0; y < 4; ++y) bs[y] = bias[n0 + wn + y * 16 + fm];
  }
  const int bb = m0 >> 11;           // epi 4 only
  const int j0 = m0 & 2047;          // epi 4 only

  if (epi == 4) {
    float izv[16];
#pragma unroll
    for (int x = 0; x < 4; ++x)
#pragma unroll
      for (int r = 0; r < 4; ++r)
        izv[x * 4 + r] = aux1[bb * 2048 + j0 + wm + x * 16 + fq * 4 + r];
#pragma unroll
    for (int x = 0; x < 4; ++x)
#pragma unroll
      for (int y = 0; y < 4; ++y) {
        union { u16 q[4]; uint2 d; } pk;
#pragma unroll
        for (int r = 0; r < 4; ++r) {
          float val = acc[x][y][r] + bs[y];
          s4[y] += val;
          pk.q[r] = f2bf(val * izv[x * 4 + r]);
        }
        int cl = wn + y * 16 + fm;
        *(uint2*)&sC[cl * 136 + wm + x * 16 + fq * 4] = pk.d;
      }
  } else {
#pragma unroll
    for (int x = 0; x < 4; ++x)
#pragma unroll
      for (int y = 0; y < 4; ++y)
#pragma unroll
        for (int r = 0; r < 4; ++r) {
          int rl = wm + x * 16 + fq * 4 + r;
          int cl = wn + y * 16 + fm;
          float val = acc[x][y][r] * scale;
          if (epi == 0) val += bs[y];
          else { val = __expf(val); s4[y] += val; }
          // XOR-swizzle the 8-u16 chunk index by fq to kill write conflicts
          int clsw = cl ^ ((rl & 12) << 1);  // = cl ^ (fq<<3)
          sC[rl * 136 + clsw] = f2bf(val);
        }
  }
  if ((epi == 3 || epi == 4) && t < 128) colred[t] = 0.f;
  __syncthreads();
  if (epi == 3 || epi == 4) {
#pragma unroll
    for (int y = 0; y < 4; ++y) {
      s4[y] += __shfl_xor(s4[y], 16, 64);
      s4[y] += __shfl_xor(s4[y], 32, 64);
    }
    if (fq == 0) {
#pragma unroll
      for (int y = 0; y < 4; ++y) atomicAdd(&colred[wn + y * 16 + fm], s4[y]);
    }
  }
  // readback + wide stores
  if (epi == 4) {
    u16* Cg = (u16*)Cout + (long)bb * (512L * 2048) + j0;
#pragma unroll
    for (int p = 0; p < 8; ++p) {
      int dl = (t >> 4) + p * 16, ch = t & 15;
      short8 v = *(const short8*)&sC[dl * 136 + ch * 8];
      *(short8*)(Cg + (long)(n0 + dl) * 2048 + ch * 8) = v;
    }
  } else {
    u16* Cg = (u16*)Cout + (long)bz * sCb + n0;
#pragma unroll
    for (int p = 0; p < 8; ++p) {
      int rl = (t >> 4) + p * 16, ch = t & 15;
      int chsw = ch ^ ((rl >> 2) & 3);
      short8 v = *(const short8*)&sC[rl * 136 + chsw * 8];
      *(short8*)(Cg + (long)(m0 + rl) * ldC + ch * 8) = v;
    }
  }
  __syncthreads();
  if (epi == 3 && t < 128) atomicAdd(&aux0[bz * 2048 + n0 + t], colred[t]);
  if (epi == 4 && t < 128) atomicAdd(&aux0[bb * 512 + n0 + t], colred[t]);
}

// ---------------- R row-sums: invR[b][i] = 1/(sum_j E*invZ + NK*eps) --------
__global__ __launch_bounds__(256) void rowsumR(const u16* __restrict__ E,
    const float* __restrict__ invZ, float* __restrict__ invR) {
  const int row = blockIdx.x;
  const int b = row >> 10;
  const u16* p = E + (long)row * NK;
  const float* zp = invZ + b * NK;
  const int t = threadIdx.x, j0 = t * 8;
  short8 v = *(const short8*)(p + j0);
  float4 z0 = *(const float4*)(zp + j0);
  float4 z1 = *(const float4*)(zp + j0 + 4);
  float sum = bf2f((u16)v[0]) * z0.x + bf2f((u16)v[1]) * z0.y +
              bf2f((u16)v[2]) * z0.z + bf2f((u16)v[3]) * z0.w +
              bf2f((u16)v[4]) * z1.x + bf2f((u16)v[5]) * z1.y +
              bf2f((u16)v[6]) * z1.z + bf2f((u16)v[7]) * z1.w;
  __shared__ float red[4];
  float a = wave_sum(sum);
  if ((t & 63) == 0) red[t >> 6] = a;
  __syncthreads();
  if (t == 0) {
    float R = red[0] + red[1] + red[2] + red[3] + 2048.f * 1e-8f;
    invR[row] = 1.0f / R;
  }
}

// ------- PV: out[b][i][d] = (sum_j E[i,j]*vTs[d,j] + eps*colV[d]) * invR[i] --
// 64x128 tile, full K=2048, direct fp32 epilogue. grid (16,4,8).
__global__ __launch_bounds__(256) void gemm_pv(const u16* __restrict__ E,
    const u16* __restrict__ V, const float* __restrict__ colV,
    const float* __restrict__ invR, float* __restrict__ out) {
  __shared__ float sO[64 * 132];
  u16* lA = (u16*)sO;            // 64 x 32
  u16* lB = (u16*)sO + 64 * 32;  // 128 x 32
  const int b = blockIdx.z;
  const int m0 = blockIdx.x * 64, n0 = blockIdx.y * 128;
  const int t = threadIdx.x, wave = t >> 6, lane = t & 63;
  const int fm = lane & 15, fq = lane >> 4;
  const int wml = (wave >> 1) * 32, wnl = (wave & 1) * 64;

  const u16* gA = E + (long)b * (1024L * 2048) +
                  (long)(m0 + wave * 16 + (lane >> 2)) * 2048 + (lane & 3) * 8;
  const u16* gB = V + (long)b * (512L * 2048) +
                  (long)(n0 + wave * 16 + (lane >> 2)) * 2048 + (lane & 3) * 8;
  u16* lAw = lA + (wave * 16) * 32;
  u16* lBw0 = lB + (wave * 16) * 32;
  u16* lBw1 = lB + (64 + wave * 16) * 32;

  floatx4 acc[2][4];
#pragma unroll
  for (int x = 0; x < 2; ++x)
#pragma unroll
    for (int y = 0; y < 4; ++y) { floatx4 z = {0.f, 0.f, 0.f, 0.f}; acc[x][y] = z; }

  for (int kt = 0; kt < 64; ++kt) {
    gload16(gA, lAw);
    gload16(gB, lBw0);
    gload16(gB + 64L * 2048, lBw1);
    gA += 32; gB += 32;
    __syncthreads();
    short8 af[2], bfr[4];
#pragma unroll
    for (int x = 0; x < 2; ++x)
      af[x] = *(const short8*)&lA[(wml + x * 16 + fm) * 32 + fq * 8];
#pragma unroll
    for (int y = 0; y < 4; ++y)
      bfr[y] = *(const short8*)&lB[(wnl + y * 16 + fm) * 32 + fq * 8];
#pragma unroll
    for (int x = 0; x < 2; ++x)
#pragma unroll
      for (int y = 0; y < 4; ++y)
        acc[x][y] = __builtin_amdgcn_mfma_f32_16x16x32_bf16(af[x], bfr[y], acc[x][y], 0, 0, 0);
    __syncthreads();
  }

  float cv[4], ir[8];
#pragma unroll
  for (int y = 0; y < 4; ++y) cv[y] = colV[b * 512 + n0 + wnl + y * 16 + fm];
#pragma unroll
  for (int x = 0; x < 2; ++x)
#pragma unroll
    for (int r = 0; r < 4; ++r)
      ir[x * 4 + r] = invR[b * 1024 + m0 + wml + x * 16 + fq * 4 + r];
#pragma unroll
  for (int x = 0; x < 2; ++x)
#pragma unroll
    for (int y = 0; y < 4; ++y)
#pragma unroll
      for (int r = 0; r < 4; ++r) {
        int rl = wml + x * 16 + fq * 4 + r;
        int cl = wnl + y * 16 + fm;
        sO[rl * 132 + cl] = (acc[x][y][r] + 1e-8f * cv[y]) * ir[x * 4 + r];
      }
  __syncthreads();
  float* og = out + (long)b * (1024L * 512) + n0;
#pragma unroll
  for (int p = 0; p < 8; ++p) {
    int rl = (t >> 5) + p * 8, ch = t & 31;
    float4 v = *(const float4*)&sO[rl * 132 + ch * 4];
    *(float4*)(og + (long)(m0 + rl) * 512 + ch * 4) = v;
  }
}

extern "C" void kernel_launch(void* const* d_in, const int* in_sizes, int n_in,
                              void* d_out, int out_size, void* d_ws, size_t ws_size,
                              hipStream_t stream) {
  const float* inputs  = (const float*)d_in[0];
  const float* context = (const float*)d_in[1];
  const float* ln_in_g = (const float*)d_in[2];
  const float* ln_in_b = (const float*)d_in[3];
  const float* ln_ctx_g = (const float*)d_in[4];
  const float* ln_ctx_b = (const float*)d_in[5];
  const float* Wq = (const float*)d_in[6];
  const float* bq = (const float*)d_in[7];
  const float* Wk = (const float*)d_in[8];
  const float* bk = (const float*)d_in[9];
  const float* Wv = (const float*)d_in[10];
  const float* bv = (const float*)d_in[11];
  float* out = (float*)d_out;

  u16* ws = (u16*)d_ws;
  u16* xb  = ws;                        // [8192][512]
  u16* qb  = xb + 8192L * 512;          // [8192][512]
  u16* cb  = qb + 8192L * 512;          // [16384][512]
  u16* wqb = cb + 16384L * 512;         // [512][512]
  u16* wkb = wqb + 512L * 512;
  u16* wvb = wkb + 512L * 512;
  u16* kb  = wvb + 512L * 512;          // [16384][512]
  u16* vTs = kb + 16384L * 512;         // [8][512][2048] (v*invZ, transposed)
  u16* E   = vTs + 8L * 512 * 2048;     // [8][1024][2048]
  float* Z    = (float*)(E + 8L * 1024 * 2048);   // [8][2048] -> invZ in place
  float* colV = Z + 8L * 2048;                    // [8][512]  (contiguous after Z)
  float* invR = colV + 8L * 512;                  // [8][1024]

  const float scale = 0.04419417382415922f;  // 512^-0.5

  // 1: both LayerNorms
  ln_fused<<<24576, 256, 0, stream>>>(inputs, ln_in_g, ln_in_b, xb,
                                      context, ln_ctx_g, ln_ctx_b, cb);
  // 2: weight cvt + zero Z/colV (20480 contiguous floats)
  prep<<<788, 256, 0, stream>>>(Wq, Wk, Wv, wqb, wkb, wvb, Z);
  // 3: q-proj (bx<64) + k-proj (bx>=64) in one launch, epi 0
  gemm_bt<<<dim3(192, 4, 1), 256, 0, stream>>>(xb, wqb, bq, qb,
      cb, wkb, bk, kb, 512, 0L, 0L, 0L, 512, 1.0f, 0, nullptr, nullptr);
  // 4: E = exp(q@k^T*scale), Z += col sums. epi 3
  gemm_bt<<<dim3(8, 16, 8), 256, 0, stream>>>(qb, kb, nullptr, E,
      nullptr, nullptr, nullptr, nullptr,
      512, 1024L * 512, 2048L * 512, 1024L * 2048, 2048, scale, 3, Z, nullptr);
  // 5: Z -> invZ
  recipf<<<64, 256, 0, stream>>>(Z);
  // 6: v-proj -> vTs (transposed, *invZ), colV += col sums. epi 4
  gemm_bt<<<dim3(128, 4, 1), 256, 0, stream>>>(cb, wvb, bv, vTs,
      nullptr, nullptr, nullptr, nullptr,
      512, 0L, 0L, 0L, 0, 1.0f, 4, colV, Z);
  // 7: invR
  rowsumR<<<8192, 256, 0, stream>>>(E, Z, invR);
  // 8: PV direct
  gemm_pv<<<dim3(16, 4, 8), 256, 0, stream>>>(E, vTs, colV, invR, out);
}